// Round 11
// baseline (450.626 us; speedup 1.0000x reference)
//
#include <hip/hip_runtime.h>

// MaxwellFFNNModel: sequential scan over T=1024, B=2048 independent rows.
// One wave per row. Latency-bound regime: all 2048 chains resident, so
// time = T x L (single-step chain latency). Every change here cuts L.
//
// Per step (r-form, tanh folded into weights -- exact algebra):
//   a   = pk[t] + gamma*W1r1            (per-lane, f32)
//   r   = rcp(exp2(c*a)+1)              (tanh(a) = 1-2r; r is what we ship)
//   pack r pairs via DPP row_shl:1 + cvt_pkrtz     [R4-proven]
//   broadcast via 8x ds_bpermute_b32 (REGISTER crosslane: no LDS arrays,
//     no memory ordering to fight -- R5/R7/R10 all died to hoisted LDS reads)
//   split-K-by-4 [R9-proven]: lane L=4o+k owns outputs {o+16m} over K-slice
//     [16k,16k+16): 32 v_dot2_f32_f16 with W2'=-2*W2 resident f16x2;
//     acc init = 0.25*b2' (quarter-fold); quad DPP reduce + cndmask select
//   r2  = rcp(exp2(c*z)+1);  v = (-2*W3[jsel])*r2
//   gamma = fma(dt, wave_sum(v), gamma + dt*b3')   (b3' add runs parallel)
//   sigma = 2.5*eps - 2*gamma
//
// R10/R7/R5 lesson: LDS-staged broadcast reads get scheduled past the store
// (absmax 361.125 signature x3) -- broadcast must be register-dataflow.
// R6 lesson: never hand-write LDS addresses. R4 lesson: readlane broadcast
// burns SGPR-hazard stalls. R1/R2 lesson: amdgpu_waves_per_eu(2,2) required
// for W2 residency. R3 lesson: pair-pack direction is row_shl:1 = 0x101.

typedef float f2 __attribute__((ext_vector_type(2)));
typedef _Float16 h2v __attribute__((ext_vector_type(2)));

#define TANH_C 2.885390081777927f   // 2*log2(e)

template<int CTRL>
__device__ __forceinline__ float dpp_add(float v) {
    int m = __builtin_amdgcn_update_dpp(0, __float_as_int(v), CTRL, 0xF, 0xF, true);
    return v + __int_as_float(m);
}

// Sum over the 4 lanes of each quad; every lane of the quad gets the sum.
__device__ __forceinline__ float quad_sum(float v) {
    v = dpp_add<0xB1>(v);   // quad_perm(1,0,3,2): L ^ 1
    v = dpp_add<0x4E>(v);   // quad_perm(2,3,0,1): L ^ 2
    return v;
}

// Full 64-lane sum, result broadcast (uniform) via readlane of lane 63.
__device__ __forceinline__ float wave_sum_bcast(float v) {
    v = dpp_add<0xB1>(v);   // pairs
    v = dpp_add<0x4E>(v);   // quads
    v = dpp_add<0x141>(v);  // row_half_mirror -> 8
    v = dpp_add<0x140>(v);  // row_mirror      -> 16
    v = dpp_add<0x142>(v);  // row_bcast15     -> lane31/63 hold sum32
    v = dpp_add<0x143>(v);  // row_bcast31     -> lane63 holds sum64
    return __int_as_float(__builtin_amdgcn_readlane(__float_as_int(v), 63));
}

__device__ __forceinline__ float rl(float v, int k) {
    return __int_as_float(__builtin_amdgcn_readlane(__float_as_int(v), k));
}

__global__ __attribute__((amdgpu_flat_work_group_size(256, 256),
                          amdgpu_waves_per_eu(2, 2)))
void maxwell_scan_kernel(
    const float* __restrict__ x,  const float* __restrict__ W1,
    const float* __restrict__ b1, const float* __restrict__ W2,
    const float* __restrict__ b2, const float* __restrict__ W3,
    const float* __restrict__ b3, float* __restrict__ out)
{
    const int lane = threadIdx.x & 63;
    const int warp = threadIdx.x >> 6;
    const int b    = (blockIdx.x << 2) + warp;      // batch row, 0..2047

    const int o = lane >> 2;          // output base index, 0..15
    const int k = lane & 3;           // K-chunk, 0..3
    const int jsel = o + 16 * k;      // this lane's final h2 index (bijection)

    // Layer-1 weights: lane = hidden unit.
    const float w1_0 = W1[lane];
    const float w1_1 = W1[64 + lane];
    const float b1j  = b1[lane];

    // Layer-3 folded constants (f32, exactly consistent):
    //   gdot = b3 + sum_j W3[j]*(1-2*r2[j]) = b3' + sum_j (-2*W3[j])*r2[j]
    const float w3p = -2.0f * W3[jsel];
    float sW3 = 0.0f;
    for (int j = 0; j < 64; ++j) sW3 += W3[j];
    const float b3p = b3[0] + sW3;

    // Layer-2 folded constants. w~ = f16(W2); -2*w~ is exact (pow2 scale).
    //   z[j] = b2[j] + sum_i w~[i][j]*(1-2r) = b2'[j] + sum_i (-2w~[i][j])*r_i
    // b2q[m] = 0.25*b2'[o+16m] folded into acc init (quad sums 4 lanes).
    int   w2h[4][8];
    float b2q[4];
#pragma unroll
    for (int m = 0; m < 4; ++m) {
        const int j = o + 16 * m;
        float cs = 0.0f;
        for (int i = 0; i < 64; ++i) cs += (float)(_Float16)W2[i * 64 + j];
        b2q[m] = 0.25f * (b2[j] + cs);
#pragma unroll
        for (int p = 0; p < 8; ++p) {
            const int i0 = 16 * k + 2 * p;
            h2v pp = { (_Float16)(-2.0f * W2[i0 * 64 + j]),
                       (_Float16)(-2.0f * W2[(i0 + 1) * 64 + j]) };
            w2h[m][p] = __builtin_bit_cast(int, pp);
        }
    }

    // bpermute byte addresses: this lane's K-slice pair-producers (even lanes).
    int baddr[8];
#pragma unroll
    for (int p = 0; p < 8; ++p) baddr[p] = (16 * k + 2 * p) << 2;

    const f2* __restrict__ xrow = (const f2*)(x) + (size_t)b * 1024; // (eps,dt)
    float*    __restrict__ orow = out + (size_t)b * 1024;

    float gamma = 0.0f;
    f2 vx = xrow[lane];                 // chunk 0: lane holds (eps,dt) of step lane

    for (int c = 0; c < 16; ++c) {
        f2 vx_next = vx;
        if (c < 15) vx_next = xrow[(c + 1) * 64 + lane];   // prefetch next chunk
        float vsig = 0.0f;

        for (int s = 0; s < 8; ++s) {          // 8 sub-chunks of 8 steps
            const int k0 = s * 8;
            // Batch scalar prep for 8 steps — independent ops, off the chain.
            float pk[8], dtk[8], sg[8], db3[8];
#pragma unroll
            for (int t = 0; t < 8; ++t) {
                const float e = rl(vx.x, k0 + t);
                dtk[t] = rl(vx.y, k0 + t);
                pk[t]  = fmaf(e, w1_0, b1j);   // layer-1 partial (gamma added later)
                sg[t]  = 2.5f * e;             // sigma partial
                db3[t] = dtk[t] * b3p;         // parallel gamma side-term
            }

            // Keep W2' pinned in arch VGPRs (empty asm, once per sub-chunk).
            asm volatile("" : "+v"(w2h[0][0]), "+v"(w2h[0][1]), "+v"(w2h[0][2]), "+v"(w2h[0][3]),
                              "+v"(w2h[0][4]), "+v"(w2h[0][5]), "+v"(w2h[0][6]), "+v"(w2h[0][7]),
                              "+v"(w2h[1][0]), "+v"(w2h[1][1]), "+v"(w2h[1][2]), "+v"(w2h[1][3]),
                              "+v"(w2h[1][4]), "+v"(w2h[1][5]), "+v"(w2h[1][6]), "+v"(w2h[1][7]));
            asm volatile("" : "+v"(w2h[2][0]), "+v"(w2h[2][1]), "+v"(w2h[2][2]), "+v"(w2h[2][3]),
                              "+v"(w2h[2][4]), "+v"(w2h[2][5]), "+v"(w2h[2][6]), "+v"(w2h[2][7]),
                              "+v"(w2h[3][0]), "+v"(w2h[3][1]), "+v"(w2h[3][2]), "+v"(w2h[3][3]),
                              "+v"(w2h[3][4]), "+v"(w2h[3][5]), "+v"(w2h[3][6]), "+v"(w2h[3][7]));

#pragma unroll
            for (int t = 0; t < 8; ++t) {
                // layer 1 in r-form (only gamma-dependent fma is on the chain)
                const float a  = fmaf(gamma, w1_1, pk[t]);
                const float ea = __builtin_amdgcn_exp2f(a * TANH_C);
                const float r  = __builtin_amdgcn_rcpf(ea + 1.0f);

                // pack r pairs: even lane 2i -> {r[2i], r[2i+1]} (row_shl:1)
                const int nb = __builtin_amdgcn_update_dpp(
                    0, __float_as_int(r), 0x101, 0xF, 0xF, true);
                const int packd = __builtin_bit_cast(
                    int, __builtin_amdgcn_cvt_pkrtz(r, __int_as_float(nb)));

                // register-dataflow broadcast: pull 8 pair-words for K-slice
                int w0 = __builtin_amdgcn_ds_bpermute(baddr[0], packd);
                int w1 = __builtin_amdgcn_ds_bpermute(baddr[1], packd);
                int w2 = __builtin_amdgcn_ds_bpermute(baddr[2], packd);
                int w3 = __builtin_amdgcn_ds_bpermute(baddr[3], packd);
                int w4 = __builtin_amdgcn_ds_bpermute(baddr[4], packd);
                int w5 = __builtin_amdgcn_ds_bpermute(baddr[5], packd);
                int w6 = __builtin_amdgcn_ds_bpermute(baddr[6], packd);
                int w7 = __builtin_amdgcn_ds_bpermute(baddr[7], packd);

                // gamma side-term runs parallel to the MLP tail
                const float gpre = gamma + db3[t];

                // layer 2: per output m, two depth-4 dot2 accumulators.
                float zacc[4];
#pragma unroll
                for (int m = 0; m < 4; ++m) {
                    float aA = b2q[m], aB = 0.0f;
                    aA = __builtin_amdgcn_fdot2(__builtin_bit_cast(h2v, w2h[m][0]),
                                                __builtin_bit_cast(h2v, w0), aA, false);
                    aB = __builtin_amdgcn_fdot2(__builtin_bit_cast(h2v, w2h[m][4]),
                                                __builtin_bit_cast(h2v, w4), aB, false);
                    aA = __builtin_amdgcn_fdot2(__builtin_bit_cast(h2v, w2h[m][1]),
                                                __builtin_bit_cast(h2v, w1), aA, false);
                    aB = __builtin_amdgcn_fdot2(__builtin_bit_cast(h2v, w2h[m][5]),
                                                __builtin_bit_cast(h2v, w5), aB, false);
                    aA = __builtin_amdgcn_fdot2(__builtin_bit_cast(h2v, w2h[m][2]),
                                                __builtin_bit_cast(h2v, w2), aA, false);
                    aB = __builtin_amdgcn_fdot2(__builtin_bit_cast(h2v, w2h[m][6]),
                                                __builtin_bit_cast(h2v, w6), aB, false);
                    aA = __builtin_amdgcn_fdot2(__builtin_bit_cast(h2v, w2h[m][3]),
                                                __builtin_bit_cast(h2v, w3), aA, false);
                    aB = __builtin_amdgcn_fdot2(__builtin_bit_cast(h2v, w2h[m][7]),
                                                __builtin_bit_cast(h2v, w7), aB, false);
                    zacc[m] = quad_sum(aA + aB);   // z[o+16m] at all quad lanes
                }

                // select m = k: lane keeps z for jsel = o + 16k.
                const float t01 = (k & 1) ? zacc[1] : zacc[0];
                const float t23 = (k & 1) ? zacc[3] : zacc[2];
                const float z   = (k & 2) ? t23 : t01;

                // layer 2 activation (r-form) + layer 3 reduce
                const float e2 = __builtin_amdgcn_exp2f(z * TANH_C);
                const float r2 = __builtin_amdgcn_rcpf(e2 + 1.0f);
                const float ws = wave_sum_bcast(r2 * w3p);
                gamma = fmaf(dtk[t], ws, gpre);

                // sigma = 2.5*eps - 2*gamma; park in lane (k0+t)
                const float sig = fmaf(-2.0f, gamma, sg[t]);
                vsig = (lane == k0 + t) ? sig : vsig;
            }
        }
        orow[c * 64 + lane] = vsig;     // coalesced 256B store per chunk
        vx = vx_next;
    }
}

extern "C" void kernel_launch(void* const* d_in, const int* in_sizes, int n_in,
                              void* d_out, int out_size, void* d_ws, size_t ws_size,
                              hipStream_t stream) {
    const float* x  = (const float*)d_in[0];
    const float* W1 = (const float*)d_in[1];
    const float* b1 = (const float*)d_in[2];
    const float* W2 = (const float*)d_in[3];
    const float* b2 = (const float*)d_in[4];
    const float* W3 = (const float*)d_in[5];
    const float* b3 = (const float*)d_in[6];
    float* out = (float*)d_out;
    (void)in_sizes; (void)n_in; (void)d_ws; (void)ws_size; (void)out_size;

    // B=2048 rows, one wave each; 4 waves/block -> 512 blocks (2 blocks/CU),
    // 8 waves/CU = 2 waves/SIMD (matches amdgpu_waves_per_eu(2,2)).
    maxwell_scan_kernel<<<512, 256, 0, stream>>>(x, W1, b1, W2, b2, W3, b3, out);
}

// Round 12
// 420.523 us; speedup vs baseline: 1.0716x; 1.0716x over previous
//
#include <hip/hip_runtime.h>

// MaxwellFFNNModel: sequential scan over T=1024, B=2048 independent rows.
// One wave per row. Latency/issue-bound scan: time = 1024 steps x per-step cost.
// Structure = R9 (fastest passing: 400us), minus ALL empty-asm W2 pin blocks.
//
// R12 experiment: the pins (16x "+v" asm, every sub-chunk, present since R2)
// are the one element common to R4/R8/R9/R11, which all show ~2x more dynamic
// VALU than written (VALUBusy-implied ~200 insts/step vs ~100 written).
// Suspected mechanism: W2 homed in AGPRs (unified file; VGPR_Count=88 can't
// contain 64 W2 regs + working set) -> accvgpr_read/write ping-pong forced
// around every pin/use; pins also wall the scheduler every sub-chunk.
// amdgpu_waves_per_eu(2,2) stays: honest 256-reg budget at 2 waves/SIMD
// removes the allocator's occupancy incentive to evict W2 (R4-proven).
//
// Layer 2 (split-K-by-4, R9-proven): lane L=4o+k owns outputs {o+16m} over
// K-slice [16k,16k+16): h1 staged in LDS (f32 store, float4 reads -- the
// TBAA-compatible pairing; R5/R7/R10 died to short/int4-typed LDS reads
// hoisted over stores), 4 ds_read_b128/step, 32 v_pk_fma_f32, quad DPP
// reduce + cndmask select (m=k) -> lane holds h2 for j = o+16k.
// Layer 3: DPP butterfly wave-sum (order-free). R6: no asm LDS addressing.

typedef float f2 __attribute__((ext_vector_type(2)));
typedef float f4 __attribute__((ext_vector_type(4)));

__device__ __forceinline__ float tanh_fast(float x) {
    // tanh(x) = 1 - 2/(e^{2x}+1); exp2 form. Saturates correctly for |x| large.
    float e = __builtin_amdgcn_exp2f(x * 2.885390081777927f); // 2*log2(e)
    float r = __builtin_amdgcn_rcpf(e + 1.0f);
    return fmaf(-2.0f, r, 1.0f);
}

template<int CTRL>
__device__ __forceinline__ float dpp_add(float v) {
    int m = __builtin_amdgcn_update_dpp(0, __float_as_int(v), CTRL, 0xF, 0xF, true);
    return v + __int_as_float(m);
}

// Sum over the 4 lanes of each quad; every lane of the quad gets the sum.
__device__ __forceinline__ float quad_sum(float v) {
    v = dpp_add<0xB1>(v);   // quad_perm(1,0,3,2): L ^ 1
    v = dpp_add<0x4E>(v);   // quad_perm(2,3,0,1): L ^ 2
    return v;
}

// Full 64-lane sum, result broadcast (uniform) via readlane of lane 63.
__device__ __forceinline__ float wave_sum_bcast(float v) {
    v = dpp_add<0xB1>(v);   // pairs
    v = dpp_add<0x4E>(v);   // quads
    v = dpp_add<0x141>(v);  // row_half_mirror -> 8
    v = dpp_add<0x140>(v);  // row_mirror      -> 16
    v = dpp_add<0x142>(v);  // row_bcast15     -> lane31/63 hold sum32
    v = dpp_add<0x143>(v);  // row_bcast31     -> lane63 holds sum64
    return __int_as_float(__builtin_amdgcn_readlane(__float_as_int(v), 63));
}

__device__ __forceinline__ float rl(float v, int k) {
    return __int_as_float(__builtin_amdgcn_readlane(__float_as_int(v), k));
}

__global__ __attribute__((amdgpu_flat_work_group_size(256, 256),
                          amdgpu_waves_per_eu(2, 2)))
void maxwell_scan_kernel(
    const float* __restrict__ x,  const float* __restrict__ W1,
    const float* __restrict__ b1, const float* __restrict__ W2,
    const float* __restrict__ b2, const float* __restrict__ W3,
    const float* __restrict__ b3, float* __restrict__ out)
{
    __shared__ __align__(16) float lds_h1[4][64];   // wave-private h1 buffers
    const int lane = threadIdx.x & 63;
    const int warp = threadIdx.x >> 6;
    const int b    = (blockIdx.x << 2) + warp;      // batch row, 0..2047

    const int o = lane >> 2;          // output base index, 0..15
    const int k = lane & 3;           // K-chunk, 0..3
    const int jsel = o + 16 * k;      // this lane's final h2 index (bijection)

    // Layer-1 weights: lane = hidden unit.
    const float w1_0 = W1[lane];
    const float w1_1 = W1[64 + lane];
    const float b1j  = b1[lane];
    // Layer-2/3 per-lane constants at the PERMUTED output index.
    const float b2s  = b2[jsel];
    const float w3s  = W3[jsel];
    const float b3s  = b3[0];

    // W2 slice for this lane: w2r[m][p] = {W2[i0][o+16m], W2[i0+1][o+16m]},
    // i0 = 16k+2p. 32 f2 = 64 registers, loop-invariant and hot; the
    // waves_per_eu(2,2) budget (256 regs) lets the allocator keep them
    // resident without asm pins (R12 experiment: pins removed).
    f2 w2r[4][8];
#pragma unroll
    for (int m = 0; m < 4; ++m) {
#pragma unroll
        for (int p = 0; p < 8; ++p) {
            const int i0 = 16 * k + 2 * p;
            const int j  = o + 16 * m;
            w2r[m][p] = (f2){ W2[i0 * 64 + j], W2[(i0 + 1) * 64 + j] };
        }
    }

    // LDS pointers: plain, non-restrict, float/float4 (R1/R8/R9-proven TBAA-safe).
    float* h1s = lds_h1[warp];
    const f4* hv = (const f4*)h1s + (k << 2);   // this lane's 64B slice

    const f2* __restrict__ xrow = (const f2*)(x) + (size_t)b * 1024; // (eps,dt)
    float*    __restrict__ orow = out + (size_t)b * 1024;

    float gamma = 0.0f;
    f2 vx = xrow[lane];                 // chunk 0: lane holds (eps,dt) of step lane

    for (int c = 0; c < 16; ++c) {
        f2 vx_next = vx;
        if (c < 15) vx_next = xrow[(c + 1) * 64 + lane];   // prefetch next chunk
        float vsig = 0.0f;

        for (int s = 0; s < 8; ++s) {          // 8 sub-chunks of 8 steps
            const int k0 = s * 8;
            // Batch scalar prep for 8 steps — independent ops, off the chain.
            float pk[8], dtk[8], sg[8];
#pragma unroll
            for (int t = 0; t < 8; ++t) {
                const float e = rl(vx.x, k0 + t);
                dtk[t] = rl(vx.y, k0 + t);
                pk[t]  = fmaf(e, w1_0, b1j);   // layer-1 partial (gamma added later)
                sg[t]  = 2.5f * e;             // sigma partial
            }

#pragma unroll
            for (int t = 0; t < 8; ++t) {
                // layer 1 (only gamma-dependent part is on the chain)
                const float h1 = tanh_fast(fmaf(gamma, w1_1, pk[t]));
                h1s[lane] = h1;
                __builtin_amdgcn_wave_barrier();   // same-wave DS in-order; fence compiler

                // layer 2, split-K: 4 ds_read_b128 of this lane's slice,
                // 32 v_pk_fma_f32 into 4 f2 accumulators (one per output m).
                f2 a0 = {0.f, 0.f}, a1 = {0.f, 0.f}, a2 = {0.f, 0.f}, a3 = {0.f, 0.f};
#pragma unroll
                for (int q = 0; q < 4; ++q) {
                    const f4 h4 = hv[q];
                    const f2 hlo = (f2){h4.x, h4.y};
                    const f2 hhi = (f2){h4.z, h4.w};
                    a0 += hlo * w2r[0][2 * q];  a0 += hhi * w2r[0][2 * q + 1];
                    a1 += hlo * w2r[1][2 * q];  a1 += hhi * w2r[1][2 * q + 1];
                    a2 += hlo * w2r[2][2 * q];  a2 += hhi * w2r[2][2 * q + 1];
                    a3 += hlo * w2r[3][2 * q];  a3 += hhi * w2r[3][2 * q + 1];
                }
                __builtin_amdgcn_wave_barrier();

                // Horizontal + quad reduction (sums K-chunks across the quad).
                float s0 = quad_sum(a0.x + a0.y);
                float s1 = quad_sum(a1.x + a1.y);
                float s2 = quad_sum(a2.x + a2.y);
                float s3 = quad_sum(a3.x + a3.y);
                // Select m = k: lane keeps output jsel = o + 16k.
                const float t01 = (k & 1) ? s1 : s0;
                const float t23 = (k & 1) ? s3 : s2;
                const float pre = (k & 2) ? t23 : t01;
                const float h2 = tanh_fast(pre + b2s);

                // layer 3 + reduce: gamma_dot (uniform across lanes;
                // DPP tree sum is permutation-invariant).
                const float gdot = wave_sum_bcast(h2 * w3s) + b3s;
                gamma = fmaf(dtk[t], gdot, gamma);

                // sigma = 2.5*eps - 2*gamma; park in lane (k0+t)
                const float sig = fmaf(-2.0f, gamma, sg[t]);
                vsig = (lane == k0 + t) ? sig : vsig;
            }
        }
        orow[c * 64 + lane] = vsig;     // coalesced 256B store per chunk
        vx = vx_next;
    }
}

extern "C" void kernel_launch(void* const* d_in, const int* in_sizes, int n_in,
                              void* d_out, int out_size, void* d_ws, size_t ws_size,
                              hipStream_t stream) {
    const float* x  = (const float*)d_in[0];
    const float* W1 = (const float*)d_in[1];
    const float* b1 = (const float*)d_in[2];
    const float* W2 = (const float*)d_in[3];
    const float* b2 = (const float*)d_in[4];
    const float* W3 = (const float*)d_in[5];
    const float* b3 = (const float*)d_in[6];
    float* out = (float*)d_out;
    (void)in_sizes; (void)n_in; (void)d_ws; (void)ws_size; (void)out_size;

    // B=2048 rows, one wave each; 4 waves/block -> 512 blocks (2 blocks/CU),
    // 8 waves/CU = 2 waves/SIMD (matches amdgpu_waves_per_eu(2,2)).
    maxwell_scan_kernel<<<512, 256, 0, stream>>>(x, W1, b1, W2, b2, W3, b3, out);
}